// Round 8
// baseline (118.360 us; speedup 1.0000x reference)
//
#include <hip/hip_runtime.h>
#include <hip/hip_fp16.h>

// Fused 3-layer ReLU-RNN + linear head, MI355X (gfx950).
// T=512, B=4096, IN=4, H1=24, H2=48, H3=24, OUT=2.
//
// ROUND 8: 4-wave pipeline, S=4 steps per barrier interval, forward-only
// cross-wave dataflow (no 1-step edges, no backward edges):
//   w0: L0(t) (2 MFMA) + L1-input W_ih1.h1(t-1) (3 MFMA, same B operand FA!)
//       -> partial1 to LDS (bias folded). x ring 8-deep, only wave touching x.
//   w1: L1 recurrence (6 MFMA): h2 = relu(partial1 + ch1.h2 + ch2.h2), split
//       accumulators + VALU add => serial chain = 1 MFMA latency.
//   w2: all L2 with re-laid-out K: [a2(48)|pad16|h3(24)|pad8]: chunks 0,1
//       (h2 from LDS, independent) computed for all 4 steps up front; serial
//       part = single chunk-2 MFMA (C = precomputed partial) + pack per step.
//   w3: output head (1 MFMA) + the only global stores.
// Barriers: 132 total (vs 512 in round 7). Raw s_barrier + lgkm-only drain
// so w0's VMEM prefetches stay in flight. All LDS rings sized so concurrent
// reader/writer slot sets are disjoint (verified mod ring size).

#define TSEQ 512
#define NBAT 4096

typedef float    f32x4 __attribute__((ext_vector_type(4)));
typedef _Float16 f16x8 __attribute__((ext_vector_type(8)));

union BFrag { f16x8 h; unsigned u[4]; };

__device__ __forceinline__ f32x4 MF(f16x8 a, f16x8 b, f32x4 c) {
  return __builtin_amdgcn_mfma_f32_16x16x32_f16(a, b, c, 0, 0, 0);
}

__device__ __forceinline__ unsigned pkh(float a, float b) {
  union { __half2 h2; unsigned u; } x;
  x.h2 = __floats2half2_rn(a, b);
  return x.u;
}
__device__ __forceinline__ unsigned pkr(float a, float b) {
  return pkh(fmaxf(a, 0.f), fmaxf(b, 0.f));
}

// lgkmcnt(0) only (vmcnt=63, expcnt=7 untouched)
#define LGKM_WAIT0 __builtin_amdgcn_s_waitcnt(0xC07F)
#define BARRIER()                                                              \
  do {                                                                         \
    __builtin_amdgcn_sched_barrier(0);                                         \
    LGKM_WAIT0;                                                                \
    __builtin_amdgcn_s_barrier();                                              \
    __builtin_amdgcn_sched_barrier(0);                                         \
  } while (0)

struct WP { const float *wih0,*whh0,*wih1,*whh1,*wih2,*whh2,*wout; };

// Concatenated zero-padded weight views:
//  L0 (K=32): k<24 -> W_hh0[m][k], k in [28,32) -> W_ih0[m][k-28]
//  L1 (K=96): k<24 -> W_ih1[m][k], k in [32,80) -> W_hh1[m][k-32]
//  L2 (K=96): NEW: k<48 -> W_ih2[m][k], k in [64,88) -> W_hh2[m][k-64]
//             (layout [a2(48)|pad16|h3(24)|pad8] so chunk2 is pure h3)
//  L3 (K=32): k<24 -> W_out[m][k], m<2
__device__ float wcat(int layer, int m, int k, const WP& P) {
  if (layer == 0) {
    if (m < 24) {
      if (k < 24) return P.whh0[m * 24 + k];
      if (k >= 28 && k < 32) return P.wih0[m * 4 + (k - 28)];
    }
    return 0.f;
  } else if (layer == 1) {
    if (m < 48) {
      if (k < 24) return P.wih1[m * 24 + k];
      if (k >= 32 && k < 80) return P.whh1[m * 48 + (k - 32)];
    }
    return 0.f;
  } else if (layer == 2) {
    if (m < 24) {
      if (k < 48) return P.wih2[m * 48 + k];
      if (k >= 64 && k < 88) return P.whh2[m * 24 + (k - 64)];
    }
    return 0.f;
  } else {
    if (m < 2 && k < 24) return P.wout[m * 24 + k];
    return 0.f;
  }
}

__device__ f16x8 afrag(int layer, int mt, int kc, const WP& P) {
  int m  = mt * 16 + (threadIdx.x & 15);
  int kb = kc * 32 + 4 * ((threadIdx.x >> 4) & 3);
  f16x8 r;
#pragma unroll
  for (int j = 0; j < 4; ++j) r[j] = (_Float16)wcat(layer, m, kb + j, P);
#pragma unroll
  for (int j = 0; j < 4; ++j) r[4 + j] = (_Float16)wcat(layer, m, kb + 16 + j, P);
  return r;
}

__device__ f32x4 cfrag(const float* b1, const float* b2, int mt, int nvalid) {
  int qq = (threadIdx.x >> 4) & 3;
  f32x4 r;
#pragma unroll
  for (int i = 0; i < 4; ++i) {
    int m = mt * 16 + 4 * qq + i;
    float v = 0.f;
    if (m < nvalid) { v = b1[m]; if (b2) v += b2[m]; }
    r[i] = v;
  }
  return r;
}

__global__ void __launch_bounds__(256)
rnn3_pipe4(const float* __restrict__ x,
           const float* __restrict__ wih0, const float* __restrict__ whh0,
           const float* __restrict__ bih0, const float* __restrict__ bhh0,
           const float* __restrict__ wih1, const float* __restrict__ whh1,
           const float* __restrict__ bih1, const float* __restrict__ bhh1,
           const float* __restrict__ wih2, const float* __restrict__ whh2,
           const float* __restrict__ bih2, const float* __restrict__ bhh2,
           const float* __restrict__ wout, const float* __restrict__ bout,
           float* __restrict__ out) {
  // LDS rings, indexed by step t mod ring. Concurrent reader/writer slot
  // sets are disjoint: sP1 w0-writes (4j-1..4j+2), w1-reads (4j-5..4j-2);
  // sH2 w1-writes (4j-5..4j-2), w2-reads (4j-9..4j-6); sH3 w2-writes
  // (4j-9..4j-6), w3-reads (4j-13..4j-10). All disjoint mod ring size.
  __shared__ f32x4 sP1[8][3][64];   // partial1(t)[mt]   24 KB
  __shared__ uint4 sH2a[16][64];    // h2[0:32] packed   16 KB
  __shared__ uint2 sH2b[16][64];    // h2[32:48] packed   8 KB
  __shared__ uint4 sH3[8][64];      // h3 packed          8 KB

  const int tid  = threadIdx.x;
  const int wid  = tid >> 6;
  const int lane = tid & 63;
  const int c = lane & 15;
  const int q = lane >> 4;
  const int b0 = blockIdx.x * 16;

  WP P{wih0, whh0, wih1, whh1, wih2, whh2, wout};
  const float4* x4 = (const float4*)x;
  float2*       o2 = (float2*)out;

  if (wid == 0) {
    // ======== w0: L0(t) + L1-input(t-1), partial1 -> LDS, x ring ========
    f16x8 A00 = afrag(0, 0, 0, P), A01 = afrag(0, 1, 0, P);
    f16x8 A1c0[3];
#pragma unroll
    for (int mt = 0; mt < 3; ++mt) A1c0[mt] = afrag(1, mt, 0, P);
    f32x4 C00 = cfrag(bih0, bhh0, 0, 24), C01 = cfrag(bih0, bhh0, 1, 24);
    f32x4 C10 = cfrag(bih1, bhh1, 0, 48), C11 = cfrag(bih1, bhh1, 1, 48);
    f32x4 C12 = cfrag(bih1, bhh1, 2, 48);

    // x ring: slot (t+1)&7 holds x(t+1) when step t runs. Init slot s<-x(s)
    // for s=1..7, slot 0 <- x(8).
    float4 xb[8];
#pragma unroll
    for (int s = 0; s < 8; ++s)
      xb[(1 + s) & 7] = x4[(size_t)(1 + s) * NBAT + b0 + c];
    float4 xv0 = x4[(size_t)b0 + c];

    unsigned fa0 = 0u, fa1 = 0u;
    unsigned fa2 = (q == 3) ? pkh(xv0.x, xv0.y) : 0u;
    unsigned fa3 = (q == 3) ? pkh(xv0.z, xv0.w) : 0u;

    // Per step t: 5 MFMAs all with B = FA(t) = [h1(t-1) | x(t)]:
    //  a10,a11 = L0(t);  p0..p2 = partial1(t-1) = W_ih1.h1(t-1)+b1
    //  (x slots hit zero-padded W columns in the L1 view). Then pack FA(t+1).
#define W0STEP(JV, SB, U)                                                      \
    {                                                                          \
      int t = 4 * (JV) + (U);                                                  \
      BFrag FAu;                                                               \
      FAu.u[0] = fa0; FAu.u[1] = fa1; FAu.u[2] = fa2; FAu.u[3] = fa3;          \
      f32x4 a10 = MF(A00, FAu.h, C00);                                         \
      f32x4 a11 = MF(A01, FAu.h, C01);                                         \
      f32x4 p0 = MF(A1c0[0], FAu.h, C10);                                      \
      f32x4 p1 = MF(A1c0[1], FAu.h, C11);                                      \
      f32x4 p2 = MF(A1c0[2], FAu.h, C12);                                      \
      float4 xs = xb[((SB) + (U) + 1) & 7];                                    \
      int tn = (t + 9 < TSEQ) ? t + 9 : TSEQ - 1;                              \
      xb[((SB) + (U) + 1) & 7] = x4[(size_t)tn * NBAT + b0 + c];               \
      if (t >= 1 && t <= TSEQ) {                                               \
        sP1[((SB) + (U) + 7) & 7][0][lane] = p0;                               \
        sP1[((SB) + (U) + 7) & 7][1][lane] = p1;                               \
        sP1[((SB) + (U) + 7) & 7][2][lane] = p2;                               \
      }                                                                        \
      fa0 = pkr(a10[0], a10[1]); fa1 = pkr(a10[2], a10[3]);                    \
      {                                                                        \
        unsigned h1b = pkr(a11[0], a11[1]), h1c = pkr(a11[2], a11[3]);         \
        fa2 = (q == 3) ? pkh(xs.x, xs.y) : h1b;                                \
        fa3 = (q == 3) ? pkh(xs.z, xs.w) : h1c;                                \
      }                                                                        \
    }

    // active j <= 128 (j==128 produces the tail partial1(511) at u=0)
#pragma unroll 1
    for (int D = 0; D < 66; ++D) {
      int j0 = 2 * D, j1 = 2 * D + 1;
      if (j0 < 129) {
        W0STEP(j0, 0, 0) W0STEP(j0, 0, 1) W0STEP(j0, 0, 2) W0STEP(j0, 0, 3)
      }
      BARRIER();
      if (j1 < 129) {
        W0STEP(j1, 4, 0) W0STEP(j1, 4, 1) W0STEP(j1, 4, 2) W0STEP(j1, 4, 3)
      }
      BARRIER();
    }
#undef W0STEP

  } else if (wid == 1) {
    // ======== w1: L1 recurrence, window t = 4j-5+u ========
    f16x8 A1c1[3], A1c2[3];
#pragma unroll
    for (int mt = 0; mt < 3; ++mt) {
      A1c1[mt] = afrag(1, mt, 1, P);
      A1c2[mt] = afrag(1, mt, 2, P);
    }
    const f32x4 Z4 = {0.f, 0.f, 0.f, 0.f};
    unsigned fb0 = 0u, fb1 = 0u, fb2 = 0u, fb3 = 0u, fc0 = 0u, fc1 = 0u;

#pragma unroll 1
    for (int j = 0; j < 132; ++j) {
      if (j >= 1 && j < 130) {
        int tb = 4 * j - 5;
        f32x4 cp0[4], cp1[4], cp2[4];
#pragma unroll
        for (int u = 0; u < 4; ++u) {
          int sl = (tb + u) & 7;
          cp0[u] = sP1[sl][0][lane];
          cp1[u] = sP1[sl][1][lane];
          cp2[u] = sP1[sl][2][lane];
        }
#pragma unroll
        for (int u = 0; u < 4; ++u) {
          int t = tb + u;
          BFrag FBu, FCu;
          FBu.u[0] = fb0; FBu.u[1] = fb1; FBu.u[2] = fb2; FBu.u[3] = fb3;
          FCu.u[0] = fc0; FCu.u[1] = fc1; FCu.u[2] = 0u; FCu.u[3] = 0u;
          f32x4 aA0 = MF(A1c1[0], FBu.h, cp0[u]);
          f32x4 aB0 = MF(A1c2[0], FCu.h, Z4);
          f32x4 aA1 = MF(A1c1[1], FBu.h, cp1[u]);
          f32x4 aB1 = MF(A1c2[1], FCu.h, Z4);
          f32x4 aA2 = MF(A1c1[2], FBu.h, cp2[u]);
          f32x4 aB2 = MF(A1c2[2], FCu.h, Z4);
          f32x4 s0 = aA0 + aB0, s1 = aA1 + aB1, s2 = aA2 + aB2;
          fb0 = pkr(s0[0], s0[1]); fb1 = pkr(s0[2], s0[3]);
          fb2 = pkr(s1[0], s1[1]); fb3 = pkr(s1[2], s1[3]);
          fc0 = pkr(s2[0], s2[1]); fc1 = pkr(s2[2], s2[3]);
          if (t < 0) { fb0 = fb1 = fb2 = fb3 = fc0 = fc1 = 0u; }
          if (t >= 0) {
            sH2a[t & 15][lane] = make_uint4(fb0, fb1, fb2, fb3);
            sH2b[t & 15][lane] = make_uint2(fc0, fc1);
          }
        }
      }
      BARRIER();
    }

  } else if (wid == 2) {
    // ======== w2: all of L2, window t = 4j-9+u ========
    f16x8 A2c0[2], A2c1[2], A2c2[2];
#pragma unroll
    for (int mt = 0; mt < 2; ++mt) {
      A2c0[mt] = afrag(2, mt, 0, P);
      A2c1[mt] = afrag(2, mt, 1, P);
      A2c2[mt] = afrag(2, mt, 2, P);
    }
    f32x4 C20 = cfrag(bih2, bhh2, 0, 24), C21 = cfrag(bih2, bhh2, 1, 24);
    unsigned fd0 = 0u, fd1 = 0u, fd2 = 0u, fd3 = 0u;

#pragma unroll 1
    for (int j = 0; j < 132; ++j) {
      if (j >= 2 && j < 131) {
        int tb = 4 * j - 9;
        uint4 hb[4]; uint2 hc[4];
#pragma unroll
        for (int u = 0; u < 4; ++u) {
          int sl = (tb + u) & 15;
          hb[u] = sH2a[sl][lane];
          hc[u] = sH2b[sl][lane];
        }
        // phase A: input partials for all 4 steps (independent 2-chains)
        f32x4 pA[4], pB[4];
#pragma unroll
        for (int u = 0; u < 4; ++u) {
          BFrag FBu, FCu;
          FBu.u[0] = hb[u].x; FBu.u[1] = hb[u].y;
          FBu.u[2] = hb[u].z; FBu.u[3] = hb[u].w;
          FCu.u[0] = hc[u].x; FCu.u[1] = hc[u].y; FCu.u[2] = 0u; FCu.u[3] = 0u;
          pA[u] = MF(A2c0[0], FBu.h, C20);
          pB[u] = MF(A2c0[1], FBu.h, C21);
          pA[u] = MF(A2c1[0], FCu.h, pA[u]);
          pB[u] = MF(A2c1[1], FCu.h, pB[u]);
        }
        // phase B: serial recurrence, one MFMA + pack per step
#pragma unroll
        for (int u = 0; u < 4; ++u) {
          int t = tb + u;
          BFrag FDu;
          FDu.u[0] = fd0; FDu.u[1] = fd1; FDu.u[2] = fd2; FDu.u[3] = fd3;
          f32x4 a30 = MF(A2c2[0], FDu.h, pA[u]);
          f32x4 a31 = MF(A2c2[1], FDu.h, pB[u]);
          fd0 = pkr(a30[0], a30[1]); fd1 = pkr(a30[2], a30[3]);
          fd2 = pkr(a31[0], a31[1]); fd3 = pkr(a31[2], a31[3]);
          if (t < 0) { fd0 = fd1 = fd2 = fd3 = 0u; }
          if (t >= 0) sH3[t & 7][lane] = make_uint4(fd0, fd1, fd2, fd3);
        }
      }
      BARRIER();
    }

  } else {
    // ======== w3: output head + stores, window t = 4j-13+u ========
    f16x8 A3 = afrag(3, 0, 0, P);
    f32x4 C3 = cfrag(bout, nullptr, 0, 2);

#pragma unroll 1
    for (int j = 0; j < 132; ++j) {
      if (j >= 3) {
        int tb = 4 * j - 13;
        uint4 rd[4];
#pragma unroll
        for (int u = 0; u < 4; ++u) rd[u] = sH3[(tb + u) & 7][lane];
#pragma unroll
        for (int u = 0; u < 4; ++u) {
          int t = tb + u;
          BFrag FDu;
          FDu.u[0] = rd[u].x; FDu.u[1] = rd[u].y;
          FDu.u[2] = rd[u].z; FDu.u[3] = rd[u].w;
          f32x4 ao = MF(A3, FDu.h, C3);
          if (t >= 0 && t < TSEQ && q == 0)
            o2[(size_t)t * NBAT + b0 + c] = make_float2(ao[0], ao[1]);
        }
      }
      BARRIER();
    }
  }
}

extern "C" void kernel_launch(void* const* d_in, const int* in_sizes, int n_in,
                              void* d_out, int out_size, void* d_ws, size_t ws_size,
                              hipStream_t stream) {
  const float* x    = (const float*)d_in[0];
  const float* wih0 = (const float*)d_in[1];
  const float* whh0 = (const float*)d_in[2];
  const float* bih0 = (const float*)d_in[3];
  const float* bhh0 = (const float*)d_in[4];
  const float* wih1 = (const float*)d_in[5];
  const float* whh1 = (const float*)d_in[6];
  const float* bih1 = (const float*)d_in[7];
  const float* bhh1 = (const float*)d_in[8];
  const float* wih2 = (const float*)d_in[9];
  const float* whh2 = (const float*)d_in[10];
  const float* bih2 = (const float*)d_in[11];
  const float* bhh2 = (const float*)d_in[12];
  const float* wout = (const float*)d_in[13];
  const float* bout = (const float*)d_in[14];
  float* out = (float*)d_out;

  rnn3_pipe4<<<dim3(NBAT / 16), dim3(256), 0, stream>>>(
      x, wih0, whh0, bih0, bhh0, wih1, whh1, bih1, bhh1,
      wih2, whh2, bih2, bhh2, wout, bout, out);
}

// Round 10
// 95.931 us; speedup vs baseline: 1.2338x; 1.2338x over previous
//
#include <hip/hip_runtime.h>
#include <hip/hip_fp16.h>

// Fused 3-layer ReLU-RNN + linear head, MI355X (gfx950).
// T=512, B=4096, IN=4, H1=24, H2=48, H3=24, OUT=2.
//
// ROUND 10 (= round 9 fixed): 8-wave pipeline (512-thr block, 2 waves/SIMD),
// S=2 steps per barrier interval, uniform-lag forward-only dataflow.
// Stage lags L: wA(h1)=0, wD/wH(partial1)=4, wB(h2)=8, wE/wF(partial2)=12,
// wC(h3)=16, wG(head+store)=20. In interval i a stage produces its items
// {2i-L, 2i-L+1}; every consumer consumes items produced at interval i-2,
// pre-read at interval i-1 (LDS latency hidden). All rings 8-deep: writer
// revisits a slot every 4 intervals, so in-flight pre-reads have a 3-interval
// safety margin. Write slots (2PB+U)&7, pre-read slots (2PB+U+6)&7 are
// compile-time (loop body covers 4 intervals; 2*i0 = 8J = 0 mod 8).
// Barrier = counted LGKM wait (drains own writes, leaves pre-reads and all
// VMEM in flight) + raw s_barrier. 268 intervals/barriers total.
// Fixes vs round 9: macro params renamed (param `u` collided with the .u
// member -> preprocessor corruption), consumer windows re-derived (round 9
// had a latent one-step skew), rings widened 4->8 for read-in-flight safety.

#define TSEQ 512
#define NBAT 4096

typedef float    f32x4 __attribute__((ext_vector_type(4)));
typedef _Float16 f16x8 __attribute__((ext_vector_type(8)));

union BFrag { f16x8 h; unsigned u[4]; };

__device__ __forceinline__ f32x4 MF(f16x8 a, f16x8 b, f32x4 c) {
  return __builtin_amdgcn_mfma_f32_16x16x32_f16(a, b, c, 0, 0, 0);
}
__device__ __forceinline__ unsigned pkh(float a, float b) {
  union { __half2 h2; unsigned u; } x;
  x.h2 = __floats2half2_rn(a, b);
  return x.u;
}
__device__ __forceinline__ unsigned pkr(float a, float b) {
  return pkh(fmaxf(a, 0.f), fmaxf(b, 0.f));
}

#define SBAR __builtin_amdgcn_sched_barrier(0)
// wait lgkmcnt(n) only (vmcnt=63, expcnt=7)
#define LGKM_WAIT(n) __builtin_amdgcn_s_waitcnt(0xC07F | ((n) << 8))
#define ENDBAR(R)                                                              \
  do {                                                                         \
    SBAR;                                                                      \
    LGKM_WAIT(R);                                                              \
    __builtin_amdgcn_s_barrier();                                              \
    SBAR;                                                                      \
  } while (0)

// ring-8 slot helpers (compile-time for constant PB,U)
#define SWS(PB, U) ((2 * (PB) + (U)) & 7)
#define SRS(PB, U) ((2 * (PB) + (U) + 6) & 7)

struct WP { const float *wih0,*whh0,*wih1,*whh1,*wih2,*whh2,*wout; };

// Concatenated zero-padded weight views:
//  L0 (K=32): k<24 -> W_hh0[m][k], k in [28,32) -> W_ih0[m][k-28]
//  L1 (K=96): k<24 -> W_ih1[m][k], k in [32,80) -> W_hh1[m][k-32]
//  L2 (K=96): k<48 -> W_ih2[m][k], k in [64,88) -> W_hh2[m][k-64]
//  L3 (K=32): k<24 -> W_out[m][k], m<2
__device__ float wcat(int layer, int m, int k, const WP& P) {
  if (layer == 0) {
    if (m < 24) {
      if (k < 24) return P.whh0[m * 24 + k];
      if (k >= 28 && k < 32) return P.wih0[m * 4 + (k - 28)];
    }
    return 0.f;
  } else if (layer == 1) {
    if (m < 48) {
      if (k < 24) return P.wih1[m * 24 + k];
      if (k >= 32 && k < 80) return P.whh1[m * 48 + (k - 32)];
    }
    return 0.f;
  } else if (layer == 2) {
    if (m < 24) {
      if (k < 48) return P.wih2[m * 48 + k];
      if (k >= 64 && k < 88) return P.whh2[m * 24 + (k - 64)];
    }
    return 0.f;
  } else {
    if (m < 2 && k < 24) return P.wout[m * 24 + k];
    return 0.f;
  }
}

__device__ f16x8 afrag(int layer, int mt, int kc, const WP& P) {
  int m  = mt * 16 + (threadIdx.x & 15);
  int kb = kc * 32 + 4 * ((threadIdx.x >> 4) & 3);
  f16x8 r;
#pragma unroll
  for (int j = 0; j < 4; ++j) r[j] = (_Float16)wcat(layer, m, kb + j, P);
#pragma unroll
  for (int j = 0; j < 4; ++j) r[4 + j] = (_Float16)wcat(layer, m, kb + 16 + j, P);
  return r;
}

__device__ f32x4 cfrag(const float* b1, const float* b2, int mt, int nvalid) {
  int qq = (threadIdx.x >> 4) & 3;
  f32x4 r;
#pragma unroll
  for (int i = 0; i < 4; ++i) {
    int m = mt * 16 + 4 * qq + i;
    float v = 0.f;
    if (m < nvalid) { v = b1[m]; if (b2) v += b2[m]; }
    r[i] = v;
  }
  return r;
}

__global__ void __launch_bounds__(512)
rnn3_pipe8(const float* __restrict__ x,
           const float* __restrict__ wih0, const float* __restrict__ whh0,
           const float* __restrict__ bih0, const float* __restrict__ bhh0,
           const float* __restrict__ wih1, const float* __restrict__ whh1,
           const float* __restrict__ bih1, const float* __restrict__ bhh1,
           const float* __restrict__ wih2, const float* __restrict__ whh2,
           const float* __restrict__ bih2, const float* __restrict__ bhh2,
           const float* __restrict__ wout, const float* __restrict__ bout,
           float* __restrict__ out) {
  __shared__ uint4 sH1[8][64];      // h1 packs                8 KB
  __shared__ f32x4 sP1[8][3][64];   // partial1 f32           24 KB
  __shared__ uint4 sH2a[8][64];     // h2[0:32] packs          8 KB
  __shared__ uint2 sH2b[8][64];     // h2[32:48] packs         4 KB
  __shared__ f32x4 sP2a[8][64];     // partial2 mt0 f32        8 KB
  __shared__ f32x4 sP2b[8][64];     // partial2 mt1 f32        8 KB
  __shared__ uint4 sH3[8][64];      // h3 packs                8 KB

  const int tid  = threadIdx.x;
  const int wid  = tid >> 6;
  const int lane = tid & 63;
  const int c = lane & 15;
  const int q = lane >> 4;
  const int b0 = blockIdx.x * 16;

  WP P{wih0, whh0, wih1, whh1, wih2, whh2, wout};
  const float4* x4 = (const float4*)x;
  float2*       o2 = (float2*)out;

  const int NJ = 67;  // 268 intervals, i = 0..267

  if (wid == 0) {
    // ========== wA: h1 recurrence (2 MFMA/step), items t = 2i+U ==========
    f16x8 A00 = afrag(0, 0, 0, P), A01 = afrag(0, 1, 0, P);
    f32x4 C00 = cfrag(bih0, bhh0, 0, 24), C01 = cfrag(bih0, bhh0, 1, 24);
    float4 xb[8];
#pragma unroll
    for (int s = 0; s < 8; ++s) xb[s] = x4[(size_t)s * NBAT + b0 + c];
    unsigned fa0 = 0u, fa1 = 0u, fa2 = 0u, fa3 = 0u;  // pure h1 packs

#define A_STEP(PB, U)                                                          \
    {                                                                          \
      float4 xs = xb[SWS(PB, U)];                                              \
      BFrag FAu;                                                               \
      FAu.u[0] = fa0; FAu.u[1] = fa1;                                          \
      FAu.u[2] = (q == 3) ? pkh(xs.x, xs.y) : fa2;                             \
      FAu.u[3] = (q == 3) ? pkh(xs.z, xs.w) : fa3;                             \
      f32x4 a10 = MF(A00, FAu.h, C00);                                         \
      f32x4 a11 = MF(A01, FAu.h, C01);                                         \
      {                                                                        \
        int t = 2 * i + (U);                                                   \
        int tn = (t + 8 < TSEQ) ? t + 8 : TSEQ - 1;                            \
        xb[SWS(PB, U)] = x4[(size_t)tn * NBAT + b0 + c];                       \
      }                                                                        \
      fa0 = pkr(a10[0], a10[1]); fa1 = pkr(a10[2], a10[3]);                    \
      fa2 = pkr(a11[0], a11[1]); fa3 = pkr(a11[2], a11[3]);                    \
      sH1[SWS(PB, U)][lane] = make_uint4(fa0, fa1, fa2, fa3);                  \
    }
#define A_BODY(PB)                                                             \
    {                                                                          \
      int i = i0 + (PB);                                                       \
      if (i <= 255) { A_STEP(PB, 0) A_STEP(PB, 1) }                            \
      ENDBAR(0);                                                               \
    }
#pragma unroll 1
    for (int J = 0; J < NJ; ++J) {
      int i0 = 4 * J;
      A_BODY(0) A_BODY(1) A_BODY(2) A_BODY(3)
    }
#undef A_BODY
#undef A_STEP

  } else if (wid == 1 || wid == 2) {
    // ====== wD (mt0,mt1) / wH (mt2): partial1(tau), tau = 2i-4+U ======
    const bool isD = (wid == 1);
    f16x8 W0 = afrag(1, isD ? 0 : 2, 0, P);
    f16x8 W1 = isD ? afrag(1, 1, 0, P) : W0;
    f32x4 Cb0 = cfrag(bih1, bhh1, isD ? 0 : 2, 48);
    f32x4 Cb1 = isD ? cfrag(bih1, bhh1, 1, 48) : Cb0;
    uint4 bufA[2], bufB[2];
    bufA[0] = bufA[1] = bufB[0] = bufB[1] = make_uint4(0u, 0u, 0u, 0u);

#define D_STEP(PB, U, CUR)                                                     \
    {                                                                          \
      BFrag FAu;                                                               \
      FAu.u[0] = CUR[U].x; FAu.u[1] = CUR[U].y;                                \
      FAu.u[2] = CUR[U].z; FAu.u[3] = CUR[U].w;                                \
      f32x4 p0 = MF(W0, FAu.h, Cb0);                                           \
      if (isD) {                                                               \
        f32x4 p1 = MF(W1, FAu.h, Cb1);                                         \
        sP1[SWS(PB, U)][0][lane] = p0;                                         \
        sP1[SWS(PB, U)][1][lane] = p1;                                         \
      } else {                                                                 \
        sP1[SWS(PB, U)][2][lane] = p0;                                         \
      }                                                                        \
    }
#define D_BODY(PB, CUR, NXT)                                                   \
    {                                                                          \
      int i = i0 + (PB);                                                       \
      if (i >= 2 && i <= 257) { D_STEP(PB, 0, CUR) D_STEP(PB, 1, CUR) }        \
      SBAR;                                                                    \
      NXT[0] = sH1[SRS(PB, 0)][lane];                                          \
      NXT[1] = sH1[SRS(PB, 1)][lane];                                          \
      ENDBAR(2);                                                               \
    }
#pragma unroll 1
    for (int J = 0; J < NJ; ++J) {
      int i0 = 4 * J;
      D_BODY(0, bufA, bufB) D_BODY(1, bufB, bufA)
      D_BODY(2, bufA, bufB) D_BODY(3, bufB, bufA)
    }
#undef D_BODY
#undef D_STEP

  } else if (wid == 3) {
    // ====== wB: h2 recurrence (6 MFMA/step), items t = 2i-8+U ======
    f16x8 A1c1[3], A1c2[3];
#pragma unroll
    for (int mt = 0; mt < 3; ++mt) {
      A1c1[mt] = afrag(1, mt, 1, P);
      A1c2[mt] = afrag(1, mt, 2, P);
    }
    const f32x4 Z4 = {0.f, 0.f, 0.f, 0.f};
    unsigned fb0 = 0u, fb1 = 0u, fb2 = 0u, fb3 = 0u, fc0 = 0u, fc1 = 0u;
    f32x4 pA[2][3], pB[2][3];
#pragma unroll
    for (int uu = 0; uu < 2; ++uu)
#pragma unroll
      for (int m = 0; m < 3; ++m) { pA[uu][m] = Z4; pB[uu][m] = Z4; }

#define B_STEP(PB, U, CUR)                                                     \
    {                                                                          \
      BFrag FBu, FCu;                                                          \
      FBu.u[0] = fb0; FBu.u[1] = fb1; FBu.u[2] = fb2; FBu.u[3] = fb3;          \
      FCu.u[0] = fc0; FCu.u[1] = fc1; FCu.u[2] = 0u; FCu.u[3] = 0u;            \
      f32x4 aA0 = MF(A1c1[0], FBu.h, CUR[U][0]);                               \
      f32x4 aB0 = MF(A1c2[0], FCu.h, Z4);                                      \
      f32x4 aA1 = MF(A1c1[1], FBu.h, CUR[U][1]);                               \
      f32x4 aB1 = MF(A1c2[1], FCu.h, Z4);                                      \
      f32x4 aA2 = MF(A1c1[2], FBu.h, CUR[U][2]);                               \
      f32x4 aB2 = MF(A1c2[2], FCu.h, Z4);                                      \
      f32x4 s0 = aA0 + aB0, s1 = aA1 + aB1, s2 = aA2 + aB2;                    \
      fb0 = pkr(s0[0], s0[1]); fb1 = pkr(s0[2], s0[3]);                        \
      fb2 = pkr(s1[0], s1[1]); fb3 = pkr(s1[2], s1[3]);                        \
      fc0 = pkr(s2[0], s2[1]); fc1 = pkr(s2[2], s2[3]);                        \
      sH2a[SWS(PB, U)][lane] = make_uint4(fb0, fb1, fb2, fb3);                 \
      sH2b[SWS(PB, U)][lane] = make_uint2(fc0, fc1);                           \
    }
#define B_BODY(PB, CUR, NXT)                                                   \
    {                                                                          \
      int i = i0 + (PB);                                                       \
      if (i >= 4 && i <= 259) { B_STEP(PB, 0, CUR) B_STEP(PB, 1, CUR) }        \
      SBAR;                                                                    \
      NXT[0][0] = sP1[SRS(PB, 0)][0][lane];                                    \
      NXT[0][1] = sP1[SRS(PB, 0)][1][lane];                                    \
      NXT[0][2] = sP1[SRS(PB, 0)][2][lane];                                    \
      NXT[1][0] = sP1[SRS(PB, 1)][0][lane];                                    \
      NXT[1][1] = sP1[SRS(PB, 1)][1][lane];                                    \
      NXT[1][2] = sP1[SRS(PB, 1)][2][lane];                                    \
      ENDBAR(6);                                                               \
    }
#pragma unroll 1
    for (int J = 0; J < NJ; ++J) {
      int i0 = 4 * J;
      B_BODY(0, pA, pB) B_BODY(1, pB, pA) B_BODY(2, pA, pB) B_BODY(3, pB, pA)
    }
#undef B_BODY
#undef B_STEP

  } else if (wid == 4 || wid == 5) {
    // ====== wE (mt0) / wF (mt1): partial2(tau), tau = 2i-12+U ======
    const int mt = (wid == 4) ? 0 : 1;
    f16x8 W0 = afrag(2, mt, 0, P), W1 = afrag(2, mt, 1, P);
    f32x4 Cb = cfrag(bih2, bhh2, mt, 24);
    uint4 haA[2], haB[2];
    uint2 hbA[2], hbB[2];
    haA[0] = haA[1] = haB[0] = haB[1] = make_uint4(0u, 0u, 0u, 0u);
    hbA[0] = hbA[1] = hbB[0] = hbB[1] = make_uint2(0u, 0u);

#define E_STEP(PB, U, CA, CB)                                                  \
    {                                                                          \
      BFrag FBu, FCu;                                                          \
      FBu.u[0] = CA[U].x; FBu.u[1] = CA[U].y;                                  \
      FBu.u[2] = CA[U].z; FBu.u[3] = CA[U].w;                                  \
      FCu.u[0] = CB[U].x; FCu.u[1] = CB[U].y;                                  \
      FCu.u[2] = 0u; FCu.u[3] = 0u;                                            \
      f32x4 p = MF(W0, FBu.h, Cb);                                             \
      p = MF(W1, FCu.h, p);                                                    \
      if (mt == 0) sP2a[SWS(PB, U)][lane] = p;                                 \
      else         sP2b[SWS(PB, U)][lane] = p;                                 \
    }
#define E_BODY(PB, CA, CB, NA, NB)                                             \
    {                                                                          \
      int i = i0 + (PB);                                                       \
      if (i >= 6 && i <= 261) { E_STEP(PB, 0, CA, CB) E_STEP(PB, 1, CA, CB) }  \
      SBAR;                                                                    \
      NA[0] = sH2a[SRS(PB, 0)][lane];                                          \
      NA[1] = sH2a[SRS(PB, 1)][lane];                                          \
      NB[0] = sH2b[SRS(PB, 0)][lane];                                          \
      NB[1] = sH2b[SRS(PB, 1)][lane];                                          \
      ENDBAR(4);                                                               \
    }
#pragma unroll 1
    for (int J = 0; J < NJ; ++J) {
      int i0 = 4 * J;
      E_BODY(0, haA, hbA, haB, hbB) E_BODY(1, haB, hbB, haA, hbA)
      E_BODY(2, haA, hbA, haB, hbB) E_BODY(3, haB, hbB, haA, hbA)
    }
#undef E_BODY
#undef E_STEP

  } else if (wid == 6) {
    // ====== wC: h3 recurrence (2 MFMA/step), items t = 2i-16+U ======
    f16x8 A2c2m0 = afrag(2, 0, 2, P), A2c2m1 = afrag(2, 1, 2, P);
    unsigned fd0 = 0u, fd1 = 0u, fd2 = 0u, fd3 = 0u;
    const f32x4 Z4 = {0.f, 0.f, 0.f, 0.f};
    f32x4 paA[2], paB[2], pbA[2], pbB[2];
    paA[0] = paA[1] = paB[0] = paB[1] = Z4;
    pbA[0] = pbA[1] = pbB[0] = pbB[1] = Z4;

#define C_STEP(PB, U, CA, CB)                                                  \
    {                                                                          \
      BFrag FDu;                                                               \
      FDu.u[0] = fd0; FDu.u[1] = fd1; FDu.u[2] = fd2; FDu.u[3] = fd3;          \
      f32x4 a30 = MF(A2c2m0, FDu.h, CA[U]);                                    \
      f32x4 a31 = MF(A2c2m1, FDu.h, CB[U]);                                    \
      fd0 = pkr(a30[0], a30[1]); fd1 = pkr(a30[2], a30[3]);                    \
      fd2 = pkr(a31[0], a31[1]); fd3 = pkr(a31[2], a31[3]);                    \
      sH3[SWS(PB, U)][lane] = make_uint4(fd0, fd1, fd2, fd3);                  \
    }
#define C_BODY(PB, CA, CB, NA, NB)                                             \
    {                                                                          \
      int i = i0 + (PB);                                                       \
      if (i >= 8 && i <= 263) { C_STEP(PB, 0, CA, CB) C_STEP(PB, 1, CA, CB) }  \
      SBAR;                                                                    \
      NA[0] = sP2a[SRS(PB, 0)][lane];                                          \
      NA[1] = sP2a[SRS(PB, 1)][lane];                                          \
      NB[0] = sP2b[SRS(PB, 0)][lane];                                          \
      NB[1] = sP2b[SRS(PB, 1)][lane];                                          \
      ENDBAR(4);                                                               \
    }
#pragma unroll 1
    for (int J = 0; J < NJ; ++J) {
      int i0 = 4 * J;
      C_BODY(0, paA, pbA, paB, pbB) C_BODY(1, paB, pbB, paA, pbA)
      C_BODY(2, paA, pbA, paB, pbB) C_BODY(3, paB, pbB, paA, pbA)
    }
#undef C_BODY
#undef C_STEP

  } else {
    // ====== wG: head (1 MFMA/step) + stores, items t = 2i-20+U ======
    f16x8 A3 = afrag(3, 0, 0, P);
    f32x4 C3 = cfrag(bout, nullptr, 0, 2);
    uint4 h3A[2], h3B[2];
    h3A[0] = h3A[1] = h3B[0] = h3B[1] = make_uint4(0u, 0u, 0u, 0u);

#define G_STEP(PB, U, CUR)                                                     \
    {                                                                          \
      BFrag FDu;                                                               \
      FDu.u[0] = CUR[U].x; FDu.u[1] = CUR[U].y;                                \
      FDu.u[2] = CUR[U].z; FDu.u[3] = CUR[U].w;                                \
      f32x4 ao = MF(A3, FDu.h, C3);                                            \
      int t = 2 * i - 20 + (U);                                                \
      if (q == 0)                                                              \
        o2[(size_t)t * NBAT + b0 + c] = make_float2(ao[0], ao[1]);             \
    }
#define G_BODY(PB, CUR, NXT)                                                   \
    {                                                                          \
      int i = i0 + (PB);                                                       \
      if (i >= 10 && i <= 265) { G_STEP(PB, 0, CUR) G_STEP(PB, 1, CUR) }       \
      SBAR;                                                                    \
      NXT[0] = sH3[SRS(PB, 0)][lane];                                          \
      NXT[1] = sH3[SRS(PB, 1)][lane];                                          \
      ENDBAR(2);                                                               \
    }
#pragma unroll 1
    for (int J = 0; J < NJ; ++J) {
      int i0 = 4 * J;
      G_BODY(0, h3A, h3B) G_BODY(1, h3B, h3A)
      G_BODY(2, h3A, h3B) G_BODY(3, h3B, h3A)
    }
#undef G_BODY
#undef G_STEP
  }
}

extern "C" void kernel_launch(void* const* d_in, const int* in_sizes, int n_in,
                              void* d_out, int out_size, void* d_ws, size_t ws_size,
                              hipStream_t stream) {
  const float* x    = (const float*)d_in[0];
  const float* wih0 = (const float*)d_in[1];
  const float* whh0 = (const float*)d_in[2];
  const float* bih0 = (const float*)d_in[3];
  const float* bhh0 = (const float*)d_in[4];
  const float* wih1 = (const float*)d_in[5];
  const float* whh1 = (const float*)d_in[6];
  const float* bih1 = (const float*)d_in[7];
  const float* bhh1 = (const float*)d_in[8];
  const float* wih2 = (const float*)d_in[9];
  const float* whh2 = (const float*)d_in[10];
  const float* bih2 = (const float*)d_in[11];
  const float* bhh2 = (const float*)d_in[12];
  const float* wout = (const float*)d_in[13];
  const float* bout = (const float*)d_in[14];
  float* out = (float*)d_out;

  rnn3_pipe8<<<dim3(NBAT / 16), dim3(512), 0, stream>>>(
      x, wih0, whh0, bih0, bhh0, wih1, whh1, bih1, bhh1,
      wih2, whh2, bih2, bhh2, wout, bout, out);
}

// Round 11
// 84.739 us; speedup vs baseline: 1.3968x; 1.1321x over previous
//
#include <hip/hip_runtime.h>
#include <hip/hip_fp16.h>

// Fused 3-layer ReLU-RNN + linear head, MI355X (gfx950).
// T=512, B=4096, IN=4, H1=24, H2=48, H3=24, OUT=2.
//
// ROUND 11: round-10 skeleton (8-wave uniform-lag forward pipeline, counted
// LGKM + raw s_barrier, pre-read one interval ahead) with S=4 steps per
// barrier interval: 140 intervals/barriers instead of 268, amortizing the
// ~500-cyc fixed per-interval overhead (barrier skew + LDS pre-read drain)
// that round-10 counters exposed (MfmaUtil 12%, VALUBusy 16%, both pipes
// mostly idle). Stage lags (steps): wA(h1)=0, wD/wH(partial1)=8, wB(h2)=16,
// wE/wF(partial2)=24, wC(h3)=32, wG(head+store)=40. Producer@i writes items
// {4i-L..4i-L+3}; consumer pre-reads@i+1 (visible after i's barrier),
// consumes@i+2. Rings 16-deep: writer revisits a slot every 4 intervals ->
// 2-interval in-flight margin for reads crossing one barrier. ENDBAR(R):
// drain own writes exactly, leave the R pre-reads in flight.

#define TSEQ 512
#define NBAT 4096

typedef float    f32x4 __attribute__((ext_vector_type(4)));
typedef _Float16 f16x8 __attribute__((ext_vector_type(8)));

union BFrag { f16x8 h; unsigned u[4]; };

__device__ __forceinline__ f32x4 MF(f16x8 a, f16x8 b, f32x4 c) {
  return __builtin_amdgcn_mfma_f32_16x16x32_f16(a, b, c, 0, 0, 0);
}
__device__ __forceinline__ unsigned pkh(float a, float b) {
  union { __half2 h2; unsigned u; } x;
  x.h2 = __floats2half2_rn(a, b);
  return x.u;
}
__device__ __forceinline__ unsigned pkr(float a, float b) {
  return pkh(fmaxf(a, 0.f), fmaxf(b, 0.f));
}

#define SBAR __builtin_amdgcn_sched_barrier(0)
// wait lgkmcnt(n) only (vmcnt=63, expcnt=7)
#define LGKM_WAIT(n) __builtin_amdgcn_s_waitcnt(0xC07F | ((n) << 8))
#define ENDBAR(R)                                                              \
  do {                                                                         \
    SBAR;                                                                      \
    LGKM_WAIT(R);                                                              \
    __builtin_amdgcn_s_barrier();                                              \
    SBAR;                                                                      \
  } while (0)

// ring-16 slot helpers (compile-time for constant PB,U; i0 = 4J so 4*i0 = 0 mod 16)
#define SW16(PB, U) ((4 * (PB) + (U)) & 15)
#define SR16(PB, U) ((4 * (PB) + (U) + 12) & 15)

struct WP { const float *wih0,*whh0,*wih1,*whh1,*wih2,*whh2,*wout; };

// Concatenated zero-padded weight views:
//  L0 (K=32): k<24 -> W_hh0[m][k], k in [28,32) -> W_ih0[m][k-28]
//  L1 (K=96): k<24 -> W_ih1[m][k], k in [32,80) -> W_hh1[m][k-32]
//  L2 (K=96): k<48 -> W_ih2[m][k], k in [64,88) -> W_hh2[m][k-64]
//  L3 (K=32): k<24 -> W_out[m][k], m<2
__device__ float wcat(int layer, int m, int k, const WP& P) {
  if (layer == 0) {
    if (m < 24) {
      if (k < 24) return P.whh0[m * 24 + k];
      if (k >= 28 && k < 32) return P.wih0[m * 4 + (k - 28)];
    }
    return 0.f;
  } else if (layer == 1) {
    if (m < 48) {
      if (k < 24) return P.wih1[m * 24 + k];
      if (k >= 32 && k < 80) return P.whh1[m * 48 + (k - 32)];
    }
    return 0.f;
  } else if (layer == 2) {
    if (m < 24) {
      if (k < 48) return P.wih2[m * 48 + k];
      if (k >= 64 && k < 88) return P.whh2[m * 24 + (k - 64)];
    }
    return 0.f;
  } else {
    if (m < 2 && k < 24) return P.wout[m * 24 + k];
    return 0.f;
  }
}

__device__ f16x8 afrag(int layer, int mt, int kc, const WP& P) {
  int m  = mt * 16 + (threadIdx.x & 15);
  int kb = kc * 32 + 4 * ((threadIdx.x >> 4) & 3);
  f16x8 r;
#pragma unroll
  for (int j = 0; j < 4; ++j) r[j] = (_Float16)wcat(layer, m, kb + j, P);
#pragma unroll
  for (int j = 0; j < 4; ++j) r[4 + j] = (_Float16)wcat(layer, m, kb + 16 + j, P);
  return r;
}

__device__ f32x4 cfrag(const float* b1, const float* b2, int mt, int nvalid) {
  int qq = (threadIdx.x >> 4) & 3;
  f32x4 r;
#pragma unroll
  for (int i = 0; i < 4; ++i) {
    int m = mt * 16 + 4 * qq + i;
    float v = 0.f;
    if (m < nvalid) { v = b1[m]; if (b2) v += b2[m]; }
    r[i] = v;
  }
  return r;
}

__global__ void __launch_bounds__(512)
rnn3_p8s4(const float* __restrict__ x,
          const float* __restrict__ wih0, const float* __restrict__ whh0,
          const float* __restrict__ bih0, const float* __restrict__ bhh0,
          const float* __restrict__ wih1, const float* __restrict__ whh1,
          const float* __restrict__ bih1, const float* __restrict__ bhh1,
          const float* __restrict__ wih2, const float* __restrict__ whh2,
          const float* __restrict__ bih2, const float* __restrict__ bhh2,
          const float* __restrict__ wout, const float* __restrict__ bout,
          float* __restrict__ out) {
  __shared__ uint4 sH1[16][64];      // h1 packs               16 KB
  __shared__ f32x4 sP1[16][3][64];   // partial1 f32           48 KB
  __shared__ uint4 sH2a[16][64];     // h2[0:32] packs         16 KB
  __shared__ uint2 sH2b[16][64];     // h2[32:48] packs         8 KB
  __shared__ f32x4 sP2a[16][64];     // partial2 mt0 f32       16 KB
  __shared__ f32x4 sP2b[16][64];     // partial2 mt1 f32       16 KB
  __shared__ uint4 sH3[16][64];      // h3 packs               16 KB

  const int tid  = threadIdx.x;
  const int wid  = tid >> 6;
  const int lane = tid & 63;
  const int c = lane & 15;
  const int q = lane >> 4;
  const int b0 = blockIdx.x * 16;

  WP P{wih0, whh0, wih1, whh1, wih2, whh2, wout};
  const float4* x4 = (const float4*)x;
  float2*       o2 = (float2*)out;

  const int NJ = 35;  // 140 intervals, i = 0..139 (last active i = 137)

  if (wid == 0) {
    // ===== wA: h1 recurrence (2 MFMA/step), items t = 4i+U, i in [0,127] =====
    f16x8 A00 = afrag(0, 0, 0, P), A01 = afrag(0, 1, 0, P);
    f32x4 C00 = cfrag(bih0, bhh0, 0, 24), C01 = cfrag(bih0, bhh0, 1, 24);
    float4 xb[16];
#pragma unroll
    for (int s = 0; s < 16; ++s) xb[s] = x4[(size_t)s * NBAT + b0 + c];
    unsigned fa0 = 0u, fa1 = 0u, fa2 = 0u, fa3 = 0u;  // pure h1 packs

#define A_STEP(PB, U)                                                          \
    {                                                                          \
      float4 xs = xb[SW16(PB, U)];                                             \
      BFrag FAu;                                                               \
      FAu.u[0] = fa0; FAu.u[1] = fa1;                                          \
      FAu.u[2] = (q == 3) ? pkh(xs.x, xs.y) : fa2;                             \
      FAu.u[3] = (q == 3) ? pkh(xs.z, xs.w) : fa3;                             \
      f32x4 a10 = MF(A00, FAu.h, C00);                                         \
      f32x4 a11 = MF(A01, FAu.h, C01);                                         \
      {                                                                        \
        int t = 4 * i + (U);                                                   \
        int tn = (t + 16 < TSEQ) ? t + 16 : TSEQ - 1;                          \
        xb[SW16(PB, U)] = x4[(size_t)tn * NBAT + b0 + c];                      \
      }                                                                        \
      fa0 = pkr(a10[0], a10[1]); fa1 = pkr(a10[2], a10[3]);                    \
      fa2 = pkr(a11[0], a11[1]); fa3 = pkr(a11[2], a11[3]);                    \
      sH1[SW16(PB, U)][lane] = make_uint4(fa0, fa1, fa2, fa3);                 \
    }
#define A_BODY(PB)                                                             \
    {                                                                          \
      int i = i0 + (PB);                                                       \
      if (i <= 127) { A_STEP(PB, 0) A_STEP(PB, 1) A_STEP(PB, 2) A_STEP(PB, 3) }\
      ENDBAR(0);                                                               \
    }
#pragma unroll 1
    for (int J = 0; J < NJ; ++J) {
      int i0 = 4 * J;
      A_BODY(0) A_BODY(1) A_BODY(2) A_BODY(3)
    }
#undef A_BODY
#undef A_STEP

  } else if (wid == 1 || wid == 2) {
    // == wD (mt0,mt1) / wH (mt2): partial1(tau), tau = 4i-8+U, i in [2,129] ==
    const bool isD = (wid == 1);
    f16x8 W0 = afrag(1, isD ? 0 : 2, 0, P);
    f16x8 W1 = isD ? afrag(1, 1, 0, P) : W0;
    f32x4 Cb0 = cfrag(bih1, bhh1, isD ? 0 : 2, 48);
    f32x4 Cb1 = isD ? cfrag(bih1, bhh1, 1, 48) : Cb0;
    uint4 bufA[4], bufB[4];
#pragma unroll
    for (int s = 0; s < 4; ++s) { bufA[s] = make_uint4(0u,0u,0u,0u); bufB[s] = make_uint4(0u,0u,0u,0u); }

#define D_STEP(PB, U, CUR)                                                     \
    {                                                                          \
      BFrag FAu;                                                               \
      FAu.u[0] = CUR[U].x; FAu.u[1] = CUR[U].y;                                \
      FAu.u[2] = CUR[U].z; FAu.u[3] = CUR[U].w;                                \
      f32x4 p0 = MF(W0, FAu.h, Cb0);                                           \
      if (isD) {                                                               \
        f32x4 p1 = MF(W1, FAu.h, Cb1);                                         \
        sP1[SW16(PB, U)][0][lane] = p0;                                        \
        sP1[SW16(PB, U)][1][lane] = p1;                                        \
      } else {                                                                 \
        sP1[SW16(PB, U)][2][lane] = p0;                                        \
      }                                                                        \
    }
#define D_BODY(PB, CUR, NXT)                                                   \
    {                                                                          \
      int i = i0 + (PB);                                                       \
      if (i >= 2 && i <= 129) {                                                \
        D_STEP(PB, 0, CUR) D_STEP(PB, 1, CUR)                                  \
        D_STEP(PB, 2, CUR) D_STEP(PB, 3, CUR)                                  \
      }                                                                        \
      SBAR;                                                                    \
      NXT[0] = sH1[SR16(PB, 0)][lane];                                         \
      NXT[1] = sH1[SR16(PB, 1)][lane];                                         \
      NXT[2] = sH1[SR16(PB, 2)][lane];                                         \
      NXT[3] = sH1[SR16(PB, 3)][lane];                                         \
      ENDBAR(4);                                                               \
    }
#pragma unroll 1
    for (int J = 0; J < NJ; ++J) {
      int i0 = 4 * J;
      D_BODY(0, bufA, bufB) D_BODY(1, bufB, bufA)
      D_BODY(2, bufA, bufB) D_BODY(3, bufB, bufA)
    }
#undef D_BODY
#undef D_STEP

  } else if (wid == 3) {
    // ===== wB: h2 recurrence (6 MFMA/step), items t = 4i-16+U, i in [4,131] =====
    f16x8 A1c1[3], A1c2[3];
#pragma unroll
    for (int mt = 0; mt < 3; ++mt) {
      A1c1[mt] = afrag(1, mt, 1, P);
      A1c2[mt] = afrag(1, mt, 2, P);
    }
    const f32x4 Z4 = {0.f, 0.f, 0.f, 0.f};
    unsigned fb0 = 0u, fb1 = 0u, fb2 = 0u, fb3 = 0u, fc0 = 0u, fc1 = 0u;
    f32x4 pA[4][3], pB[4][3];
#pragma unroll
    for (int s = 0; s < 4; ++s)
#pragma unroll
      for (int m = 0; m < 3; ++m) { pA[s][m] = Z4; pB[s][m] = Z4; }

#define B_STEP(PB, U, CUR)                                                     \
    {                                                                          \
      BFrag FBu, FCu;                                                          \
      FBu.u[0] = fb0; FBu.u[1] = fb1; FBu.u[2] = fb2; FBu.u[3] = fb3;          \
      FCu.u[0] = fc0; FCu.u[1] = fc1; FCu.u[2] = 0u; FCu.u[3] = 0u;            \
      f32x4 aB0 = MF(A1c2[0], FCu.h, Z4);                                      \
      f32x4 aB1 = MF(A1c2[1], FCu.h, Z4);                                      \
      f32x4 aB2 = MF(A1c2[2], FCu.h, Z4);                                      \
      f32x4 aA0 = MF(A1c1[0], FBu.h, CUR[U][0]);                               \
      f32x4 aA1 = MF(A1c1[1], FBu.h, CUR[U][1]);                               \
      f32x4 aA2 = MF(A1c1[2], FBu.h, CUR[U][2]);                               \
      f32x4 s0 = aA0 + aB0, s1 = aA1 + aB1, s2 = aA2 + aB2;                    \
      fb0 = pkr(s0[0], s0[1]); fb1 = pkr(s0[2], s0[3]);                        \
      fb2 = pkr(s1[0], s1[1]); fb3 = pkr(s1[2], s1[3]);                        \
      fc0 = pkr(s2[0], s2[1]); fc1 = pkr(s2[2], s2[3]);                        \
      sH2a[SW16(PB, U)][lane] = make_uint4(fb0, fb1, fb2, fb3);                \
      sH2b[SW16(PB, U)][lane] = make_uint2(fc0, fc1);                          \
    }
#define B_BODY(PB, CUR, NXT)                                                   \
    {                                                                          \
      int i = i0 + (PB);                                                       \
      if (i >= 4 && i <= 131) {                                                \
        B_STEP(PB, 0, CUR) B_STEP(PB, 1, CUR)                                  \
        B_STEP(PB, 2, CUR) B_STEP(PB, 3, CUR)                                  \
      }                                                                        \
      SBAR;                                                                    \
      NXT[0][0] = sP1[SR16(PB, 0)][0][lane];                                   \
      NXT[0][1] = sP1[SR16(PB, 0)][1][lane];                                   \
      NXT[0][2] = sP1[SR16(PB, 0)][2][lane];                                   \
      NXT[1][0] = sP1[SR16(PB, 1)][0][lane];                                   \
      NXT[1][1] = sP1[SR16(PB, 1)][1][lane];                                   \
      NXT[1][2] = sP1[SR16(PB, 1)][2][lane];                                   \
      NXT[2][0] = sP1[SR16(PB, 2)][0][lane];                                   \
      NXT[2][1] = sP1[SR16(PB, 2)][1][lane];                                   \
      NXT[2][2] = sP1[SR16(PB, 2)][2][lane];                                   \
      NXT[3][0] = sP1[SR16(PB, 3)][0][lane];                                   \
      NXT[3][1] = sP1[SR16(PB, 3)][1][lane];                                   \
      NXT[3][2] = sP1[SR16(PB, 3)][2][lane];                                   \
      ENDBAR(12);                                                              \
    }
#pragma unroll 1
    for (int J = 0; J < NJ; ++J) {
      int i0 = 4 * J;
      B_BODY(0, pA, pB) B_BODY(1, pB, pA) B_BODY(2, pA, pB) B_BODY(3, pB, pA)
    }
#undef B_BODY
#undef B_STEP

  } else if (wid == 4 || wid == 5) {
    // == wE (mt0) / wF (mt1): partial2(tau), tau = 4i-24+U, i in [6,133] ==
    const int mt = (wid == 4) ? 0 : 1;
    f16x8 W0 = afrag(2, mt, 0, P), W1 = afrag(2, mt, 1, P);
    f32x4 Cb = cfrag(bih2, bhh2, mt, 24);
    uint4 haA[4], haB[4];
    uint2 hbA[4], hbB[4];
#pragma unroll
    for (int s = 0; s < 4; ++s) {
      haA[s] = make_uint4(0u,0u,0u,0u); haB[s] = make_uint4(0u,0u,0u,0u);
      hbA[s] = make_uint2(0u,0u);       hbB[s] = make_uint2(0u,0u);
    }

#define E_STEP(PB, U, CA, CB)                                                  \
    {                                                                          \
      BFrag FBu, FCu;                                                          \
      FBu.u[0] = CA[U].x; FBu.u[1] = CA[U].y;                                  \
      FBu.u[2] = CA[U].z; FBu.u[3] = CA[U].w;                                  \
      FCu.u[0] = CB[U].x; FCu.u[1] = CB[U].y;                                  \
      FCu.u[2] = 0u; FCu.u[3] = 0u;                                            \
      f32x4 p = MF(W0, FBu.h, Cb);                                             \
      p = MF(W1, FCu.h, p);                                                    \
      if (mt == 0) sP2a[SW16(PB, U)][lane] = p;                                \
      else         sP2b[SW16(PB, U)][lane] = p;                                \
    }
#define E_BODY(PB, CA, CB, NA, NB)                                             \
    {                                                                          \
      int i = i0 + (PB);                                                       \
      if (i >= 6 && i <= 133) {                                                \
        E_STEP(PB, 0, CA, CB) E_STEP(PB, 1, CA, CB)                            \
        E_STEP(PB, 2, CA, CB) E_STEP(PB, 3, CA, CB)                            \
      }                                                                        \
      SBAR;                                                                    \
      NA[0] = sH2a[SR16(PB, 0)][lane];                                         \
      NA[1] = sH2a[SR16(PB, 1)][lane];                                         \
      NA[2] = sH2a[SR16(PB, 2)][lane];                                         \
      NA[3] = sH2a[SR16(PB, 3)][lane];                                         \
      NB[0] = sH2b[SR16(PB, 0)][lane];                                         \
      NB[1] = sH2b[SR16(PB, 1)][lane];                                         \
      NB[2] = sH2b[SR16(PB, 2)][lane];                                         \
      NB[3] = sH2b[SR16(PB, 3)][lane];                                         \
      ENDBAR(8);                                                               \
    }
#pragma unroll 1
    for (int J = 0; J < NJ; ++J) {
      int i0 = 4 * J;
      E_BODY(0, haA, hbA, haB, hbB) E_BODY(1, haB, hbB, haA, hbA)
      E_BODY(2, haA, hbA, haB, hbB) E_BODY(3, haB, hbB, haA, hbA)
    }
#undef E_BODY
#undef E_STEP

  } else if (wid == 6) {
    // ===== wC: h3 recurrence (2 MFMA/step), items t = 4i-32+U, i in [8,135] =====
    f16x8 A2c2m0 = afrag(2, 0, 2, P), A2c2m1 = afrag(2, 1, 2, P);
    unsigned fd0 = 0u, fd1 = 0u, fd2 = 0u, fd3 = 0u;
    const f32x4 Z4 = {0.f, 0.f, 0.f, 0.f};
    f32x4 paA[4], paB[4], pbA[4], pbB[4];
#pragma unroll
    for (int s = 0; s < 4; ++s) { paA[s] = Z4; paB[s] = Z4; pbA[s] = Z4; pbB[s] = Z4; }

#define C_STEP(PB, U, CA, CB)                                                  \
    {                                                                          \
      BFrag FDu;                                                               \
      FDu.u[0] = fd0; FDu.u[1] = fd1; FDu.u[2] = fd2; FDu.u[3] = fd3;          \
      f32x4 a30 = MF(A2c2m0, FDu.h, CA[U]);                                    \
      f32x4 a31 = MF(A2c2m1, FDu.h, CB[U]);                                    \
      fd0 = pkr(a30[0], a30[1]); fd1 = pkr(a30[2], a30[3]);                    \
      fd2 = pkr(a31[0], a31[1]); fd3 = pkr(a31[2], a31[3]);                    \
      sH3[SW16(PB, U)][lane] = make_uint4(fd0, fd1, fd2, fd3);                 \
    }
#define C_BODY(PB, CA, CB, NA, NB)                                             \
    {                                                                          \
      int i = i0 + (PB);                                                       \
      if (i >= 8 && i <= 135) {                                                \
        C_STEP(PB, 0, CA, CB) C_STEP(PB, 1, CA, CB)                            \
        C_STEP(PB, 2, CA, CB) C_STEP(PB, 3, CA, CB)                            \
      }                                                                        \
      SBAR;                                                                    \
      NA[0] = sP2a[SR16(PB, 0)][lane];                                         \
      NA[1] = sP2a[SR16(PB, 1)][lane];                                         \
      NA[2] = sP2a[SR16(PB, 2)][lane];                                         \
      NA[3] = sP2a[SR16(PB, 3)][lane];                                         \
      NB[0] = sP2b[SR16(PB, 0)][lane];                                         \
      NB[1] = sP2b[SR16(PB, 1)][lane];                                         \
      NB[2] = sP2b[SR16(PB, 2)][lane];                                         \
      NB[3] = sP2b[SR16(PB, 3)][lane];                                         \
      ENDBAR(8);                                                               \
    }
#pragma unroll 1
    for (int J = 0; J < NJ; ++J) {
      int i0 = 4 * J;
      C_BODY(0, paA, pbA, paB, pbB) C_BODY(1, paB, pbB, paA, pbA)
      C_BODY(2, paA, pbA, paB, pbB) C_BODY(3, paB, pbB, paA, pbA)
    }
#undef C_BODY
#undef C_STEP

  } else {
    // ===== wG: head (1 MFMA/step) + stores, items t = 4i-40+U, i in [10,137] =====
    f16x8 A3 = afrag(3, 0, 0, P);
    f32x4 C3 = cfrag(bout, nullptr, 0, 2);
    uint4 h3A[4], h3B[4];
#pragma unroll
    for (int s = 0; s < 4; ++s) { h3A[s] = make_uint4(0u,0u,0u,0u); h3B[s] = make_uint4(0u,0u,0u,0u); }

#define G_STEP(PB, U, CUR)                                                     \
    {                                                                          \
      BFrag FDu;                                                               \
      FDu.u[0] = CUR[U].x; FDu.u[1] = CUR[U].y;                                \
      FDu.u[2] = CUR[U].z; FDu.u[3] = CUR[U].w;                                \
      f32x4 ao = MF(A3, FDu.h, C3);                                            \
      int t = 4 * i - 40 + (U);                                                \
      if (q == 0)                                                              \
        o2[(size_t)t * NBAT + b0 + c] = make_float2(ao[0], ao[1]);             \
    }
#define G_BODY(PB, CUR, NXT)                                                   \
    {                                                                          \
      int i = i0 + (PB);                                                       \
      if (i >= 10 && i <= 137) {                                               \
        G_STEP(PB, 0, CUR) G_STEP(PB, 1, CUR)                                  \
        G_STEP(PB, 2, CUR) G_STEP(PB, 3, CUR)                                  \
      }                                                                        \
      SBAR;                                                                    \
      NXT[0] = sH3[SR16(PB, 0)][lane];                                         \
      NXT[1] = sH3[SR16(PB, 1)][lane];                                         \
      NXT[2] = sH3[SR16(PB, 2)][lane];                                         \
      NXT[3] = sH3[SR16(PB, 3)][lane];                                         \
      ENDBAR(4);                                                               \
    }
#pragma unroll 1
    for (int J = 0; J < NJ; ++J) {
      int i0 = 4 * J;
      G_BODY(0, h3A, h3B) G_BODY(1, h3B, h3A)
      G_BODY(2, h3A, h3B) G_BODY(3, h3B, h3A)
    }
#undef G_BODY
#undef G_STEP
  }
}

extern "C" void kernel_launch(void* const* d_in, const int* in_sizes, int n_in,
                              void* d_out, int out_size, void* d_ws, size_t ws_size,
                              hipStream_t stream) {
  const float* x    = (const float*)d_in[0];
  const float* wih0 = (const float*)d_in[1];
  const float* whh0 = (const float*)d_in[2];
  const float* bih0 = (const float*)d_in[3];
  const float* bhh0 = (const float*)d_in[4];
  const float* wih1 = (const float*)d_in[5];
  const float* whh1 = (const float*)d_in[6];
  const float* bih1 = (const float*)d_in[7];
  const float* bhh1 = (const float*)d_in[8];
  const float* wih2 = (const float*)d_in[9];
  const float* whh2 = (const float*)d_in[10];
  const float* bih2 = (const float*)d_in[11];
  const float* bhh2 = (const float*)d_in[12];
  const float* wout = (const float*)d_in[13];
  const float* bout = (const float*)d_in[14];
  float* out = (float*)d_out;

  rnn3_p8s4<<<dim3(NBAT / 16), dim3(512), 0, stream>>>(
      x, wih0, whh0, bih0, bhh0, wih1, whh1, bih1, bhh1,
      wih2, whh2, bih2, bhh2, wout, bout, out);
}